// Round 2
// baseline (428.512 us; speedup 1.0000x reference)
//
#include <hip/hip_runtime.h>

// WaveConv1d on MI355X — round 13: einsum_v7 (deep pipeline, counted vmcnt).
//   out = x + idwt(E1(lo4)-lo4, E2(h4)-h4, 0, 0, 0)
// r12 post-mortem: v5 and v6 (different LDS schedules) both 113us => not LDS-
// throughput bound. All pipes <60%: latency/sync-bound. Root cause: per-chunk
// __syncthreads() compiles to s_waitcnt vmcnt(0)+s_barrier -> prefetch drains
// every chunk, memory duty cycle ~30% (2.0 TB/s of 6.3). v7: 4-deep register
// FIFO; loads for chunk ch+4 issued at ch, stay in flight across 3 barriers;
// barrier is raw asm "s_waitcnt lgkmcnt(0); s_barrier" (NO vmcnt drain); the
// ds_write of slot ch+1 gets a compiler-derived counted vmcnt (~18). Slots use
// literal indices (macro) so the FIFO stays in registers.

#define NROWS 4096          // B*C
#define MODES 522

#define M1 4101
#define M2 2056
#define M3 1033
#define M4 522

typedef unsigned int  uint;
typedef unsigned short ushort;

__constant__ float c_dlo[12] = {
  -0.00107730108499558f,  0.004777257511010651f,  0.0005538422009938016f,
  -0.031582039318031156f, 0.02752286553001629f,   0.09750160558707936f,
  -0.12976686756709563f,  -0.22626469396516913f,  0.3152503517092432f,
   0.7511339080215775f,   0.4946238903983854f,    0.11154074335008017f };
__constant__ float c_dhi[12] = {
  -0.11154074335008017f,  0.4946238903983854f,   -0.7511339080215775f,
   0.3152503517092432f,   0.22626469396516913f,  -0.12976686756709563f,
  -0.09750160558707936f,  0.02752286553001629f,   0.031582039318031156f,
   0.0005538422009938016f,-0.004777257511010651f, -0.00107730108499558f };
// Analysis (time-reversed) filters
__constant__ float c_alo[12] = {
   0.11154074335008017f,  0.4946238903983854f,    0.7511339080215775f,
   0.3152503517092432f,  -0.22626469396516913f,  -0.12976686756709563f,
   0.09750160558707936f,  0.02752286553001629f,  -0.031582039318031156f,
   0.0005538422009938016f, 0.004777257511010651f, -0.00107730108499558f };
__constant__ float c_ahi[12] = {
  -0.00107730108499558f, -0.004777257511010651f,  0.0005538422009938016f,
   0.031582039318031156f, 0.02752286553001629f,  -0.09750160558707936f,
  -0.12976686756709563f,  0.22626469396516913f,   0.3152503517092432f,
  -0.7511339080215775f,   0.4946238903983854f,   -0.11154074335008017f };

__device__ __forceinline__ ushort f2bf(float f) {
    uint b = __float_as_uint(f);
    uint r = (b + 0x7fffu + ((b >> 16) & 1u)) >> 16;
    return (ushort)r;
}

// One lo-only analysis level LDS->LDS, interior fast path (no reflect).
__device__ __forceinline__
void dwt_lo_lds(const float* __restrict__ src, int n, int m,
                float* __restrict__ dst, int tid)
{
    int jhi = (n - 2) >> 1;
    for (int j = tid; j < m; j += 256) {
        float a = 0.f;
        if (j >= 5 && j <= jhi) {
            const float* s = src + 2 * j - 10;
#pragma unroll
            for (int t = 0; t < 12; ++t) a += s[t] * c_alo[t];
        } else {
            int base = 2 * j - 10;
#pragma unroll
            for (int t = 0; t < 12; ++t) {
                int u = base + t;
                u = (u < 0) ? (-1 - u) : u;
                u = (u >= n) ? (2 * n - 1 - u) : u;
                a += src[u] * c_alo[t];
            }
        }
        dst[j] = a;
    }
}

// Fused forward DWT, lo-chain only: x -> (lo4, h4). One block per row.
__global__ __launch_bounds__(256)
void dwt_fused2(const float* __restrict__ x,
                float* __restrict__ lo4g, float* __restrict__ h4g)
{
    __shared__ float X[8192];
    __shared__ float LA[4104];
    int row = blockIdx.x, tid = threadIdx.x;

    const float4* xr = (const float4*)(x + (size_t)row * 8192);
    float4* Xv = (float4*)X;
#pragma unroll
    for (int i = 0; i < 8; ++i) Xv[tid + 256 * i] = xr[tid + 256 * i];
    __syncthreads();

    dwt_lo_lds(X,  8192, M1, LA, tid);
    __syncthreads();
    dwt_lo_lds(LA, M1,   M2, X,  tid);
    __syncthreads();
    dwt_lo_lds(X,  M2,   M3, LA, tid);
    __syncthreads();

    float* lo4r = lo4g + (size_t)row * M4;
    float* h4r  = h4g  + (size_t)row * M4;
    int jhi = (M3 - 2) >> 1;
    for (int j = tid; j < M4; j += 256) {
        float alo = 0.f, ahi = 0.f;
        if (j >= 5 && j <= jhi) {
            const float* s = LA + 2 * j - 10;
#pragma unroll
            for (int t = 0; t < 12; ++t) {
                float v = s[t];
                alo += v * c_alo[t]; ahi += v * c_ahi[t];
            }
        } else {
            int base = 2 * j - 10;
#pragma unroll
            for (int t = 0; t < 12; ++t) {
                int u = base + t;
                u = (u < 0) ? (-1 - u) : u;
                u = (u >= M3) ? (2 * M3 - 1 - u) : u;
                float v = LA[u];
                alo += v * c_alo[t]; ahi += v * c_ahi[t];
            }
        }
        lo4r[j] = alo; h4r[j] = ahi;
    }
}

// xpose2: [b][c][k] fp32 -> bf16 xT [c][g=4][k=522][b4] (g = b>>2, b4 = b&3).
// One block per (c, tensor). ALSO zero-fills dlo/dh (2*SZ contiguous floats)
// for einsum_v7's atomicAdd accumulation (stream order guarantees completion
// before einsum launches).
__global__ __launch_bounds__(256)
void xpose2(const float* __restrict__ lo4, const float* __restrict__ h4,
            ushort* __restrict__ xlT, ushort* __restrict__ xhT,
            float* __restrict__ dzero)
{
    __shared__ float L[16][528];
    int c = blockIdx.x;
    const float* src = blockIdx.y ? h4 : lo4;
    ushort*      dst = blockIdx.y ? xhT : xlT;
    int t = threadIdx.x;

    // zero dlo+dh: 2*SZ floats over 512 blocks x 256 thr
    {
        const size_t nz = ((size_t)2 * NROWS * M4) / 4;
        size_t gid = ((size_t)blockIdx.y * gridDim.x + blockIdx.x) * 256 + t;
        float4 z4 = make_float4(0.f, 0.f, 0.f, 0.f);
        float4* zp = (float4*)dzero;
        for (size_t i = gid; i < nz; i += (size_t)512 * 256) zp[i] = z4;
    }

#pragma unroll
    for (int b = 0; b < 16; ++b)
        for (int k = t; k < MODES; k += 256)
            L[b][k] = src[((size_t)b * 256 + c) * MODES + k];
    __syncthreads();

#pragma unroll
    for (int g = 0; g < 4; ++g) {
        for (int k = t; k < MODES; k += 256) {
            ushort4 v;
            v.x = f2bf(L[4*g+0][k]);
            v.y = f2bf(L[4*g+1][k]);
            v.z = f2bf(L[4*g+2][k]);
            v.w = f2bf(L[4*g+3][k]);
            *(ushort4*)&dst[(((size_t)c * 4 + g) * MODES + k) * 4] = v;
        }
    }
}

// Delta-IDWT: A = dlo-lo4, Hs = dh-h4; lvl4 full -> lvl3,2,1 lo-only -> +x.
__global__ __launch_bounds__(256)
void idwt_delta2(const float* __restrict__ dlo, const float* __restrict__ dh,
                 const float* __restrict__ lo4, const float* __restrict__ h4,
                 const float* __restrict__ x,   float* __restrict__ out)
{
    __shared__ float A[2056];
    __shared__ float B[4104];
    __shared__ float Hs[528];
    int row = blockIdx.x, tid = threadIdx.x;

    for (int i = tid; i < M4; i += 256) {
        size_t idx = (size_t)row * M4 + i;
        A[i]  = dlo[idx] - lo4[idx];
        Hs[i] = dh[idx]  - h4[idx];
    }
    __syncthreads();

    for (int jj = tid; jj < M4 - 5; jj += 256) {
        float e = 0.f, od = 0.f;
#pragma unroll
        for (int s = 0; s < 6; ++s) {
            float xv = A[jj + s], hv = Hs[jj + s];
            e  += xv * c_dlo[2*s+1] + hv * c_dhi[2*s+1];
            od += xv * c_dlo[2*s]   + hv * c_dhi[2*s];
        }
        B[2*jj] = e; B[2*jj+1] = od;
    }
    __syncthreads();

    for (int jj = tid; jj < M3 - 5; jj += 256) {
        float e = 0.f, od = 0.f;
#pragma unroll
        for (int s = 0; s < 6; ++s) {
            float xv = B[jj + s];
            e  += xv * c_dlo[2*s+1];
            od += xv * c_dlo[2*s];
        }
        A[2*jj] = e; A[2*jj+1] = od;
    }
    __syncthreads();

    for (int jj = tid; jj < M2 - 5; jj += 256) {
        float e = 0.f, od = 0.f;
#pragma unroll
        for (int s = 0; s < 6; ++s) {
            float xv = A[jj + s];
            e  += xv * c_dlo[2*s+1];
            od += xv * c_dlo[2*s];
        }
        B[2*jj] = e; B[2*jj+1] = od;
    }
    __syncthreads();

    const float2* x2 = (const float2*)(x + (size_t)row * 8192);
    float2* o2 = (float2*)(out + (size_t)row * 8192);
    for (int jj = tid; jj < M1 - 5; jj += 256) {
        float e = 0.f, od = 0.f;
#pragma unroll
        for (int s = 0; s < 6; ++s) {
            float xv = B[jj + s];
            e  += xv * c_dlo[2*s+1];
            od += xv * c_dlo[2*s];
        }
        float2 xv2 = x2[jj];
        o2[jj] = make_float2(xv2.x + e, xv2.y + od);
    }
}

// Dual einsum v7: 4-deep register FIFO + raw barrier (counted vmcnt survives).
// dlo[b,o,k] += sum_{i in half} x[b,i,k]*w[i,o,k]   (atomicAdd; dlo/dh zeroed
// by xpose2).
// Grid 2304: wg<1152 -> (xlT,w1,dlo), else (xhT,w2,dh). Per tensor:
//   wg<1024: kt=wg&7 (XCD-pinned), r=wg>>3, oq=r&63, ih=r>>6
//   else:    kt=8 -> kbase=MODES-64, u=wg-1024, oq=u&63, ih=u>>6
// Each block: 32 chunks x 4 i over i in [ih*128, ih*128+128).
// Slot lifecycle: slot s holds chunk c (c==s mod 4). At chunk ch (d=ch&3):
//   compute buf[ch&1]; load chunk ch+4 -> slot d (freed: chunk ch's data was
//   ds_written at ch-1); ds_write slot (d+1)&3 (chunk ch+1, loaded at ch-3,
//   long arrived -> counted vmcnt, no stall) -> buf[ch&1 ^1];
//   "s_waitcnt lgkmcnt(0); s_barrier" (NO vmcnt drain - loads for ch+1..ch+4
//   stay in flight across the barrier).
// kt=8 k-overlap with kt=7: only lanes with kbase+lane>=512 write.
__global__ __launch_bounds__(256, 4)
void einsum_v7(const ushort* __restrict__ xlT, const ushort* __restrict__ xhT,
               const float* __restrict__ w1,   const float* __restrict__ w2,
               float* __restrict__ dlo, float* __restrict__ dh)
{
    __shared__ ushort Xb[2][4096];   // [buf][ ((il*4+g)*64 + kk)*4 + b ]  16 KB
    __shared__ float  Wb[2][1024];   // [buf][ (il*64 + kk)*4 + j ]         8 KB

    int wg = blockIdx.x;
    int e = (wg >= 1152); if (e) wg -= 1152;
    const ushort* xT = e ? xhT : xlT;
    const float*  w  = e ? w2  : w1;
    float* outp      = e ? dh  : dlo;

    int kt, oq, ih;
    if (wg < 1024) { kt = wg & 7; int r2 = wg >> 3; oq = r2 & 63; ih = r2 >> 6; }
    else           { kt = 8; int u = wg - 1024;     oq = u & 63;  ih = u >> 6; }
    int kbase = (kt < 8) ? kt * 64 : (MODES - 64);
    int lane = threadIdx.x & 63;
    int wv   = threadIdx.x >> 6;
    int o    = oq * 4;
    int t    = threadIdx.x;
    int i0   = ih * 128;

    // x staging decode: run = t>>4 -> (xil = run>>2, g = run&3); piece = t&15
    int run = t >> 4, piece = t & 15;
    int xil = run >> 2, g = run & 3;
    const ushort* xrunb = xT + (((size_t)(i0 + xil) * 4 + g) * MODES + kbase) * 4
                             + piece * 16;
    const size_t xistr = (size_t)4 * MODES * 4;           // ushorts per i

    // w staging decode: wr = t>>6 (= il), kk = t&63; 4 dword loads, one per j.
    int wr = t >> 6, kk = t & 63;
    const float* wrunb = w + ((size_t)(i0 + wr) * 256 + o) * MODES + kbase + kk;
    const size_t wistr = (size_t)256 * MODES;             // floats per i

    float acc[4][4];
#pragma unroll
    for (int q = 0; q < 4; ++q)
#pragma unroll
        for (int j = 0; j < 4; ++j) acc[q][j] = 0.f;

    // 4-deep register FIFO (static indices only).
    uint4 sx0[4], sx1[4]; float4 sw[4];

    // ---- prologue: issue loads for chunks 0..3 ----
#pragma unroll
    for (int d = 0; d < 4; ++d) {
        const ushort* xs = xrunb + (size_t)d * 4 * xistr;
        sx0[d] = *(const uint4*)(xs);
        sx1[d] = *(const uint4*)(xs + 8);
        const float* wsv = wrunb + (size_t)d * 4 * wistr;
        sw[d] = make_float4(wsv[0], wsv[MODES], wsv[2*MODES], wsv[3*MODES]);
    }
    // write chunk 0 (slot 0) to buf 0; compiler emits counted vmcnt (~18).
    {
        uint4* xd = (uint4*)&Xb[0][t * 16];
        xd[0] = sx0[0]; xd[1] = sx1[0];
        *(float4*)&Wb[0][t * 4] = sw[0];
    }
    asm volatile("s_waitcnt lgkmcnt(0)\n\ts_barrier" ::: "memory");

#define CHUNK_BODY(J)                                                         \
    {                                                                         \
        const int ch = chb + (J);                                             \
        _Pragma("unroll")                                                     \
        for (int ii = 0; ii < 4; ++ii) {                                      \
            uint2 xp = *(const uint2*)&Xb[(J)&1][(((ii*4)+wv)*64+lane)*4];    \
            float4 w4 = *(const float4*)&Wb[(J)&1][(ii*64+lane)*4];           \
            float x0 = __uint_as_float(xp.x << 16);                           \
            float x1 = __uint_as_float(xp.x & 0xffff0000u);                   \
            float x2 = __uint_as_float(xp.y << 16);                           \
            float x3 = __uint_as_float(xp.y & 0xffff0000u);                   \
            acc[0][0] += x0*w4.x; acc[0][1] += x0*w4.y;                       \
            acc[0][2] += x0*w4.z; acc[0][3] += x0*w4.w;                       \
            acc[1][0] += x1*w4.x; acc[1][1] += x1*w4.y;                       \
            acc[1][2] += x1*w4.z; acc[1][3] += x1*w4.w;                       \
            acc[2][0] += x2*w4.x; acc[2][1] += x2*w4.y;                       \
            acc[2][2] += x2*w4.z; acc[2][3] += x2*w4.w;                       \
            acc[3][0] += x3*w4.x; acc[3][1] += x3*w4.y;                       \
            acc[3][2] += x3*w4.z; acc[3][3] += x3*w4.w;                       \
        }                                                                     \
        if (ch < 28) {                                                        \
            const ushort* xs = xrunb + (size_t)(ch + 4) * 4 * xistr;          \
            sx0[(J)] = *(const uint4*)(xs);                                   \
            sx1[(J)] = *(const uint4*)(xs + 8);                               \
            const float* wsv = wrunb + (size_t)(ch + 4) * 4 * wistr;          \
            sw[(J)] = make_float4(wsv[0], wsv[MODES], wsv[2*MODES],           \
                                  wsv[3*MODES]);                              \
        }                                                                     \
        if (ch < 31) {                                                        \
            uint4* xd = (uint4*)&Xb[((J)&1)^1][t * 16];                       \
            xd[0] = sx0[((J)+1)&3]; xd[1] = sx1[((J)+1)&3];                   \
            *(float4*)&Wb[((J)&1)^1][t * 4] = sw[((J)+1)&3];                  \
        }                                                                     \
        asm volatile("s_waitcnt lgkmcnt(0)\n\ts_barrier" ::: "memory");       \
    }

    for (int m = 0; m < 8; ++m) {
        const int chb = m * 4;
        CHUNK_BODY(0)
        CHUNK_BODY(1)
        CHUNK_BODY(2)
        CHUNK_BODY(3)
    }
#undef CHUNK_BODY

    // atomic accumulate (each element hit exactly twice: ih=0 and ih=1).
    // kt=8 overlaps kt=7 for k in [458,512): those lanes must not write.
    bool wrk = (kt < 8) || (kbase + lane >= 512);
    if (wrk) {
#pragma unroll
        for (int q = 0; q < 4; ++q) {
            int b = 4 * wv + q;
#pragma unroll
            for (int j = 0; j < 4; ++j)
                atomicAdd(&outp[((size_t)b * 256 + o + j) * MODES + kbase + lane],
                          acc[q][j]);
        }
    }
}

extern "C" void kernel_launch(void* const* d_in, const int* in_sizes, int n_in,
                              void* d_out, int out_size, void* d_ws, size_t ws_size,
                              hipStream_t stream)
{
    const float* x  = (const float*)d_in[0];
    const float* w1 = (const float*)d_in[1];
    const float* w2 = (const float*)d_in[2];
    float* out = (float*)d_out;
    float* ws  = (float*)d_ws;

    const size_t SZ = (size_t)NROWS * M4;   // 2,138,112
    float* lo4 = ws;
    float* h4  = lo4 + SZ;
    float* dlo = h4  + SZ;
    float* dh  = dlo + SZ;                   // dlo,dh contiguous (zeroed together)
    ushort* xlT = (ushort*)(dh + SZ);        // SZ ushorts
    ushort* xhT = xlT + SZ;                  // SZ ushorts

    dim3 blk(256);

    dwt_fused2<<<NROWS, blk, 0, stream>>>(x, lo4, h4);
    xpose2<<<dim3(256, 2), blk, 0, stream>>>(lo4, h4, xlT, xhT, dlo);
    einsum_v7<<<2304, blk, 0, stream>>>(xlT, xhT, w1, w2, dlo, dh);
    idwt_delta2<<<NROWS, blk, 0, stream>>>(dlo, dh, lo4, h4, x, out);
}

// Round 3
// 266.787 us; speedup vs baseline: 1.6062x; 1.6062x over previous
//
#include <hip/hip_runtime.h>

// WaveConv1d on MI355X — round 14: einsum_v8 (global_load_lds 3-buffer pipeline).
//   out = x + idwt(E1(lo4)-lo4, E2(h4)-h4, 0, 0, 0)
// r13 post-mortem: v7's register FIFO spilled (VGPR=64 reported, WRITE_SIZE
// 36->578 MB = scratch traffic) -> 295us. Theory (latency/sync-bound) untested.
// v8 keeps the deep pipeline but holds it in LDS via global_load_lds (zero
// staging VGPRs, no ds_write, no vmcnt(0)->ds_write->lgkm chain):
//   3 buffers x (8KB x + 4KB w) = 36 KB, 4 blocks/CU.
//   loop: STAGE(ch+2) -> compute(ch) -> s_waitcnt vmcnt(6) lgkmcnt(0); s_barrier
//   (6 DMA ops/wave/chunk stay in flight across every barrier; drained to 0
//   only at the tail). Wb uses v5 j-strided layout: gl4 staging is 256B-
//   contiguous global segments and compute w-reads are conflict-free b32.
//   (w rows are 8B-aligned (MODES=522 odd*2) -> width-16 illegal for w; x is
//   16B-aligned everywhere -> width-16 ok.)

#define NROWS 4096          // B*C
#define MODES 522

#define M1 4101
#define M2 2056
#define M3 1033
#define M4 522

typedef unsigned int  uint;
typedef unsigned short ushort;

__constant__ float c_dlo[12] = {
  -0.00107730108499558f,  0.004777257511010651f,  0.0005538422009938016f,
  -0.031582039318031156f, 0.02752286553001629f,   0.09750160558707936f,
  -0.12976686756709563f,  -0.22626469396516913f,  0.3152503517092432f,
   0.7511339080215775f,   0.4946238903983854f,    0.11154074335008017f };
__constant__ float c_dhi[12] = {
  -0.11154074335008017f,  0.4946238903983854f,   -0.7511339080215775f,
   0.3152503517092432f,   0.22626469396516913f,  -0.12976686756709563f,
  -0.09750160558707936f,  0.02752286553001629f,   0.031582039318031156f,
   0.0005538422009938016f,-0.004777257511010651f, -0.00107730108499558f };
// Analysis (time-reversed) filters
__constant__ float c_alo[12] = {
   0.11154074335008017f,  0.4946238903983854f,    0.7511339080215775f,
   0.3152503517092432f,  -0.22626469396516913f,  -0.12976686756709563f,
   0.09750160558707936f,  0.02752286553001629f,  -0.031582039318031156f,
   0.0005538422009938016f, 0.004777257511010651f, -0.00107730108499558f };
__constant__ float c_ahi[12] = {
  -0.00107730108499558f, -0.004777257511010651f,  0.0005538422009938016f,
   0.031582039318031156f, 0.02752286553001629f,  -0.09750160558707936f,
  -0.12976686756709563f,  0.22626469396516913f,   0.3152503517092432f,
  -0.7511339080215775f,   0.4946238903983854f,   -0.11154074335008017f };

__device__ __forceinline__ ushort f2bf(float f) {
    uint b = __float_as_uint(f);
    uint r = (b + 0x7fffu + ((b >> 16) & 1u)) >> 16;
    return (ushort)r;
}

// async DMA global->LDS. LDS dest: wave-uniform base, lane l writes base+l*sz.
// Global src is per-lane. size must be a literal (4 or 16).
__device__ __forceinline__ void gl16(const ushort* g, ushort* l) {
    __builtin_amdgcn_global_load_lds(
        (const __attribute__((address_space(1))) void*)g,
        (__attribute__((address_space(3))) void*)l, 16, 0, 0);
}
__device__ __forceinline__ void gl4(const float* g, float* l) {
    __builtin_amdgcn_global_load_lds(
        (const __attribute__((address_space(1))) void*)g,
        (__attribute__((address_space(3))) void*)l, 4, 0, 0);
}

// One lo-only analysis level LDS->LDS, interior fast path (no reflect).
__device__ __forceinline__
void dwt_lo_lds(const float* __restrict__ src, int n, int m,
                float* __restrict__ dst, int tid)
{
    int jhi = (n - 2) >> 1;
    for (int j = tid; j < m; j += 256) {
        float a = 0.f;
        if (j >= 5 && j <= jhi) {
            const float* s = src + 2 * j - 10;
#pragma unroll
            for (int t = 0; t < 12; ++t) a += s[t] * c_alo[t];
        } else {
            int base = 2 * j - 10;
#pragma unroll
            for (int t = 0; t < 12; ++t) {
                int u = base + t;
                u = (u < 0) ? (-1 - u) : u;
                u = (u >= n) ? (2 * n - 1 - u) : u;
                a += src[u] * c_alo[t];
            }
        }
        dst[j] = a;
    }
}

// Fused forward DWT, lo-chain only: x -> (lo4, h4). One block per row.
__global__ __launch_bounds__(256)
void dwt_fused2(const float* __restrict__ x,
                float* __restrict__ lo4g, float* __restrict__ h4g)
{
    __shared__ float X[8192];
    __shared__ float LA[4104];
    int row = blockIdx.x, tid = threadIdx.x;

    const float4* xr = (const float4*)(x + (size_t)row * 8192);
    float4* Xv = (float4*)X;
#pragma unroll
    for (int i = 0; i < 8; ++i) Xv[tid + 256 * i] = xr[tid + 256 * i];
    __syncthreads();

    dwt_lo_lds(X,  8192, M1, LA, tid);
    __syncthreads();
    dwt_lo_lds(LA, M1,   M2, X,  tid);
    __syncthreads();
    dwt_lo_lds(X,  M2,   M3, LA, tid);
    __syncthreads();

    float* lo4r = lo4g + (size_t)row * M4;
    float* h4r  = h4g  + (size_t)row * M4;
    int jhi = (M3 - 2) >> 1;
    for (int j = tid; j < M4; j += 256) {
        float alo = 0.f, ahi = 0.f;
        if (j >= 5 && j <= jhi) {
            const float* s = LA + 2 * j - 10;
#pragma unroll
            for (int t = 0; t < 12; ++t) {
                float v = s[t];
                alo += v * c_alo[t]; ahi += v * c_ahi[t];
            }
        } else {
            int base = 2 * j - 10;
#pragma unroll
            for (int t = 0; t < 12; ++t) {
                int u = base + t;
                u = (u < 0) ? (-1 - u) : u;
                u = (u >= M3) ? (2 * M3 - 1 - u) : u;
                float v = LA[u];
                alo += v * c_alo[t]; ahi += v * c_ahi[t];
            }
        }
        lo4r[j] = alo; h4r[j] = ahi;
    }
}

// xpose2: [b][c][k] fp32 -> bf16 xT [c][g=4][k=522][b4] (g = b>>2, b4 = b&3).
// One block per (c, tensor). ALSO zero-fills dlo/dh (2*SZ contiguous floats)
// for einsum_v8's atomicAdd accumulation (stream order guarantees completion
// before einsum launches).
__global__ __launch_bounds__(256)
void xpose2(const float* __restrict__ lo4, const float* __restrict__ h4,
            ushort* __restrict__ xlT, ushort* __restrict__ xhT,
            float* __restrict__ dzero)
{
    __shared__ float L[16][528];
    int c = blockIdx.x;
    const float* src = blockIdx.y ? h4 : lo4;
    ushort*      dst = blockIdx.y ? xhT : xlT;
    int t = threadIdx.x;

    // zero dlo+dh: 2*SZ floats over 512 blocks x 256 thr
    {
        const size_t nz = ((size_t)2 * NROWS * M4) / 4;
        size_t gid = ((size_t)blockIdx.y * gridDim.x + blockIdx.x) * 256 + t;
        float4 z4 = make_float4(0.f, 0.f, 0.f, 0.f);
        float4* zp = (float4*)dzero;
        for (size_t i = gid; i < nz; i += (size_t)512 * 256) zp[i] = z4;
    }

#pragma unroll
    for (int b = 0; b < 16; ++b)
        for (int k = t; k < MODES; k += 256)
            L[b][k] = src[((size_t)b * 256 + c) * MODES + k];
    __syncthreads();

#pragma unroll
    for (int g = 0; g < 4; ++g) {
        for (int k = t; k < MODES; k += 256) {
            ushort4 v;
            v.x = f2bf(L[4*g+0][k]);
            v.y = f2bf(L[4*g+1][k]);
            v.z = f2bf(L[4*g+2][k]);
            v.w = f2bf(L[4*g+3][k]);
            *(ushort4*)&dst[(((size_t)c * 4 + g) * MODES + k) * 4] = v;
        }
    }
}

// Delta-IDWT: A = dlo-lo4, Hs = dh-h4; lvl4 full -> lvl3,2,1 lo-only -> +x.
__global__ __launch_bounds__(256)
void idwt_delta2(const float* __restrict__ dlo, const float* __restrict__ dh,
                 const float* __restrict__ lo4, const float* __restrict__ h4,
                 const float* __restrict__ x,   float* __restrict__ out)
{
    __shared__ float A[2056];
    __shared__ float B[4104];
    __shared__ float Hs[528];
    int row = blockIdx.x, tid = threadIdx.x;

    for (int i = tid; i < M4; i += 256) {
        size_t idx = (size_t)row * M4 + i;
        A[i]  = dlo[idx] - lo4[idx];
        Hs[i] = dh[idx]  - h4[idx];
    }
    __syncthreads();

    for (int jj = tid; jj < M4 - 5; jj += 256) {
        float e = 0.f, od = 0.f;
#pragma unroll
        for (int s = 0; s < 6; ++s) {
            float xv = A[jj + s], hv = Hs[jj + s];
            e  += xv * c_dlo[2*s+1] + hv * c_dhi[2*s+1];
            od += xv * c_dlo[2*s]   + hv * c_dhi[2*s];
        }
        B[2*jj] = e; B[2*jj+1] = od;
    }
    __syncthreads();

    for (int jj = tid; jj < M3 - 5; jj += 256) {
        float e = 0.f, od = 0.f;
#pragma unroll
        for (int s = 0; s < 6; ++s) {
            float xv = B[jj + s];
            e  += xv * c_dlo[2*s+1];
            od += xv * c_dlo[2*s];
        }
        A[2*jj] = e; A[2*jj+1] = od;
    }
    __syncthreads();

    for (int jj = tid; jj < M2 - 5; jj += 256) {
        float e = 0.f, od = 0.f;
#pragma unroll
        for (int s = 0; s < 6; ++s) {
            float xv = A[jj + s];
            e  += xv * c_dlo[2*s+1];
            od += xv * c_dlo[2*s];
        }
        B[2*jj] = e; B[2*jj+1] = od;
    }
    __syncthreads();

    const float2* x2 = (const float2*)(x + (size_t)row * 8192);
    float2* o2 = (float2*)(out + (size_t)row * 8192);
    for (int jj = tid; jj < M1 - 5; jj += 256) {
        float e = 0.f, od = 0.f;
#pragma unroll
        for (int s = 0; s < 6; ++s) {
            float xv = B[jj + s];
            e  += xv * c_dlo[2*s+1];
            od += xv * c_dlo[2*s];
        }
        float2 xv2 = x2[jj];
        o2[jj] = make_float2(xv2.x + e, xv2.y + od);
    }
}

// Dual einsum v8: global_load_lds 3-buffer pipeline, counted vmcnt.
// dlo[b,o,k] += sum_{i in half} x[b,i,k]*w[i,o,k]   (atomicAdd; dlo/dh zeroed
// by xpose2).
// Grid 2304: wg<1152 -> (xlT,w1,dlo), else (xhT,w2,dh). Per tensor:
//   wg<1024: kt=wg&7 (XCD-pinned), r=wg>>3, oq=r&63, ih=r>>6
//   else:    kt=8 -> kbase=MODES-64, u=wg-1024, oq=u&63, ih=u>>6
// Each block: 32 chunks x 4 i over i in [ih*128, ih*128+128).
// LDS: 3 x (Xb 8KB [ ((il*4+g)*64+kk)*4+b ] bf16 + Wb 4KB [ (il*4+j)*64+kk ]
// f32) = 36 KB. Staging per wave per chunk (wave wv owns il=wv):
//   2x gl16 (x: lanes 0-31 -> g=2n seg, 32-63 -> g=2n+1; 16B-aligned)
//   4x gl4  (w: one per j; 256B-contiguous global row segments)
// Loop: STAGE(ch+2) -> compute(ch) -> "s_waitcnt vmcnt(6) lgkmcnt(0); s_barrier"
// (chunk ch+2's 6 DMAs stay in flight; ch+1 guaranteed landed). Tail drains 0.
// kt=8 k-overlap with kt=7: only lanes with kbase+lane>=512 write.
__global__ __launch_bounds__(256)
void einsum_v8(const ushort* __restrict__ xlT, const ushort* __restrict__ xhT,
               const float* __restrict__ w1,   const float* __restrict__ w2,
               float* __restrict__ dlo, float* __restrict__ dh)
{
    __shared__ ushort XbA[3 * 4096];   // 3 x 8 KB
    __shared__ float  WbA[3 * 1024];   // 3 x 4 KB

    int wg = blockIdx.x;
    int e = (wg >= 1152); if (e) wg -= 1152;
    const ushort* xT = e ? xhT : xlT;
    const float*  w  = e ? w2  : w1;
    float* outp      = e ? dh  : dlo;

    int kt, oq, ih;
    if (wg < 1024) { kt = wg & 7; int r2 = wg >> 3; oq = r2 & 63; ih = r2 >> 6; }
    else           { kt = 8; int u = wg - 1024;     oq = u & 63;  ih = u >> 6; }
    int kbase = (kt < 8) ? kt * 64 : (MODES - 64);
    int lane = threadIdx.x & 63;
    int wv   = threadIdx.x >> 6;
    int o    = oq * 4;
    int i0   = ih * 128;

    // per-lane global bases (wave wv stages il=wv of each chunk)
    // x: ushort units. i stride = 4*MODES*4 = 8352; g stride = MODES*4 = 2088;
    //    chunk stride = 4*8352 = 33408. 16B-aligned per lane.
    const ushort* xgl = xT + (size_t)(i0 + wv) * 8352
                           + (size_t)(lane >> 5) * 2088
                           + (size_t)kbase * 4 + (size_t)(lane & 31) * 8;
    // w: float units. chunk stride = 4*256*MODES = 534528.
    const float* wgl = w + ((size_t)(i0 + wv) * 256 + o) * MODES + kbase + lane;

    // wave-uniform LDS bases (element units)
    ushort* xlds = XbA + wv * 1024;    // wave region = 2048 B
    float*  wlds = WbA + wv * 256;     // wave region = 1024 B

#define STAGE(bi, c) do {                                                     \
        const ushort* xa_ = xgl + (size_t)(c) * 33408;                        \
        ushort* lx_ = xlds + (bi) * 4096;                                     \
        gl16(xa_, lx_);                                                       \
        gl16(xa_ + 2 * 2088, lx_ + 512);                                      \
        const float* wa_ = wgl + (size_t)(c) * 534528;                        \
        float* lw_ = wlds + (bi) * 1024;                                      \
        gl4(wa_,             lw_);                                            \
        gl4(wa_ + MODES,     lw_ + 64);                                       \
        gl4(wa_ + 2 * MODES, lw_ + 128);                                      \
        gl4(wa_ + 3 * MODES, lw_ + 192);                                      \
    } while (0)

    float acc[4][4];
#pragma unroll
    for (int q = 0; q < 4; ++q)
#pragma unroll
        for (int j = 0; j < 4; ++j) acc[q][j] = 0.f;

    // prologue: chunks 0,1 in flight; wait chunk 0 (leave chunk 1's 6)
    STAGE(0, 0);
    STAGE(1, 1);
    asm volatile("s_waitcnt vmcnt(6)\n\ts_barrier" ::: "memory");

    int cur = 0, nb = 2;
    for (int ch = 0; ch < 32; ++ch) {
        if (ch < 30) STAGE(nb, ch + 2);

        const ushort* Xc = XbA + (size_t)cur * 4096;
        const float*  Wc = WbA + (size_t)cur * 1024;
#pragma unroll
        for (int ii = 0; ii < 4; ++ii) {
            uint2 xp = *(const uint2*)&Xc[(((ii * 4) + wv) * 64 + lane) * 4];
            float wr0 = Wc[(ii * 4 + 0) * 64 + lane];
            float wr1 = Wc[(ii * 4 + 1) * 64 + lane];
            float wr2 = Wc[(ii * 4 + 2) * 64 + lane];
            float wr3 = Wc[(ii * 4 + 3) * 64 + lane];
            float x0 = __uint_as_float(xp.x << 16);
            float x1 = __uint_as_float(xp.x & 0xffff0000u);
            float x2 = __uint_as_float(xp.y << 16);
            float x3 = __uint_as_float(xp.y & 0xffff0000u);
            acc[0][0] += x0 * wr0; acc[0][1] += x0 * wr1;
            acc[0][2] += x0 * wr2; acc[0][3] += x0 * wr3;
            acc[1][0] += x1 * wr0; acc[1][1] += x1 * wr1;
            acc[1][2] += x1 * wr2; acc[1][3] += x1 * wr3;
            acc[2][0] += x2 * wr0; acc[2][1] += x2 * wr1;
            acc[2][2] += x2 * wr2; acc[2][3] += x2 * wr3;
            acc[3][0] += x3 * wr0; acc[3][1] += x3 * wr1;
            acc[3][2] += x3 * wr2; acc[3][3] += x3 * wr3;
        }

        if (ch < 30)
            asm volatile("s_waitcnt vmcnt(6) lgkmcnt(0)\n\ts_barrier" ::: "memory");
        else if (ch == 30)
            asm volatile("s_waitcnt vmcnt(0) lgkmcnt(0)\n\ts_barrier" ::: "memory");

        cur = (cur == 2) ? 0 : cur + 1;
        nb  = (nb  == 2) ? 0 : nb  + 1;
    }
#undef STAGE

    // atomic accumulate (each element hit exactly twice: ih=0 and ih=1).
    // kt=8 overlaps kt=7 for k in [458,512): those lanes must not write.
    bool wrk = (kt < 8) || (kbase + lane >= 512);
    if (wrk) {
#pragma unroll
        for (int q = 0; q < 4; ++q) {
            int b = 4 * wv + q;
#pragma unroll
            for (int j = 0; j < 4; ++j)
                atomicAdd(&outp[((size_t)b * 256 + o + j) * MODES + kbase + lane],
                          acc[q][j]);
        }
    }
}

extern "C" void kernel_launch(void* const* d_in, const int* in_sizes, int n_in,
                              void* d_out, int out_size, void* d_ws, size_t ws_size,
                              hipStream_t stream)
{
    const float* x  = (const float*)d_in[0];
    const float* w1 = (const float*)d_in[1];
    const float* w2 = (const float*)d_in[2];
    float* out = (float*)d_out;
    float* ws  = (float*)d_ws;

    const size_t SZ = (size_t)NROWS * M4;   // 2,138,112
    float* lo4 = ws;
    float* h4  = lo4 + SZ;
    float* dlo = h4  + SZ;
    float* dh  = dlo + SZ;                   // dlo,dh contiguous (zeroed together)
    ushort* xlT = (ushort*)(dh + SZ);        // SZ ushorts
    ushort* xhT = xlT + SZ;                  // SZ ushorts

    dim3 blk(256);

    dwt_fused2<<<NROWS, blk, 0, stream>>>(x, lo4, h4);
    xpose2<<<dim3(256, 2), blk, 0, stream>>>(lo4, h4, xlT, xhT, dlo);
    einsum_v8<<<2304, blk, 0, stream>>>(xlT, xhT, w1, w2, dlo, dh);
    idwt_delta2<<<NROWS, blk, 0, stream>>>(dlo, dh, lo4, h4, x, out);
}